// Round 3
// baseline (74.055 us; speedup 1.0000x reference)
//
#include <hip/hip_runtime.h>
#include <math.h>

constexpr int B_ = 64, Q_ = 900, N_ = 100, C_ = 256;
constexpr float EPSF = 1e-6f;
constexpr float BOX_W = 5.0f, GIOU_W = 2.0f, CLS_W = 1.0f;
constexpr int KP = 15;  // preds per lane: 64 lanes * 15 >= 900

__device__ __forceinline__ float giou_f(float px0, float py0, float px1, float py1, float pa,
                                        float tx0, float ty0, float tx1, float ty1, float ta) {
    float ltx = fmaxf(px0, tx0), lty = fmaxf(py0, ty0);
    float rbx = fminf(px1, tx1), rby = fminf(py1, ty1);
    float w = fmaxf(rbx - ltx, 0.0f), h = fmaxf(rby - lty, 0.0f);
    float inter = w * h;
    float uni = pa + ta - inter;
    float iou = inter / (uni + EPSF);
    float ex0 = fminf(px0, tx0), ey0 = fminf(py0, ty0);
    float ex1 = fmaxf(px1, tx1), ey1 = fmaxf(py1, ty1);
    float ew = fmaxf(ex1 - ex0, 0.0f), eh = fmaxf(ey1 - ey0, 0.0f);
    float earea = ew * eh;
    return iou - (earea - uni) / (earea + EPSF);
}

// order-preserving float->uint; key = (ord << 32) | ~q  => u64 max == (max value, min index)
__device__ __forceinline__ unsigned int f2ord(float f) {
    unsigned int u = __float_as_uint(f);
    return (u & 0x80000000u) ? ~u : (u | 0x80000000u);
}
__device__ __forceinline__ unsigned long long mkkey(float g, int q) {
    return ((unsigned long long)f2ord(g) << 32) | (unsigned int)(~(unsigned int)q);
}

// ---------------- kernel 1: per-column unconstrained top-2 ----------------
__global__ __launch_bounds__(64) void cand_kernel(
    const float* __restrict__ pred_boxes,   // [B,Q,4] cxcywh
    const float* __restrict__ target_boxes, // [B,N,4] xyxy
    unsigned long long* __restrict__ c1,    // [B*N]
    unsigned long long* __restrict__ c2)    // [B*N]
{
    const int bn = blockIdx.x;
    const int b = bn / N_;
    const int lane = threadIdx.x;

    const float* t = target_boxes + (size_t)bn * 4;
    float tx0 = t[0], ty0 = t[1], tx1 = t[2], ty1 = t[3];
    float ta = (tx1 - tx0) * (ty1 - ty0);

    const float4* pbv = (const float4*)(pred_boxes + (size_t)b * Q_ * 4);
    unsigned long long k1 = 0ull, k2 = 0ull;
    #pragma unroll
    for (int k = 0; k < KP; ++k) {
        int q = lane + (k << 6);
        if (q < Q_) {
            float4 c = pbv[q];
            float x0 = c.x - 0.5f * c.z, y0 = c.y - 0.5f * c.w;
            float x1 = c.x + 0.5f * c.z, y1 = c.y + 0.5f * c.w;
            float pa = (x1 - x0) * (y1 - y0);
            float g = giou_f(x0, y0, x1, y1, pa, tx0, ty0, tx1, ty1, ta);
            unsigned long long kk = mkkey(g, q);
            if (kk > k1) { k2 = k1; k1 = kk; }
            else if (kk > k2) { k2 = kk; }
        }
    }
    #pragma unroll
    for (int off = 32; off >= 1; off >>= 1) {
        unsigned long long o1 = __shfl_xor(k1, off);
        unsigned long long o2 = __shfl_xor(k2, off);
        unsigned long long n1 = (k1 > o1) ? k1 : o1;
        unsigned long long mn = (k1 > o1) ? o1 : k1;
        unsigned long long mx2 = (k2 > o2) ? k2 : o2;
        unsigned long long n2 = (mn > mx2) ? mn : mx2;
        k1 = n1; k2 = n2;
    }
    if (lane == 0) { c1[bn] = k1; c2[bn] = k2; }
}

// -------- kernel 2: register/ballot greedy resolve + box loss + BCE --------
__global__ __launch_bounds__(256) void resolve_loss_kernel(
    const float* __restrict__ pred_boxes,
    const float* __restrict__ pred_logits,
    const float* __restrict__ target_boxes,
    const int*   __restrict__ target_labels,
    const unsigned long long* __restrict__ c1g,
    const unsigned long long* __restrict__ c2g,
    double* __restrict__ partial)   // [B]
{
    const int b = blockIdx.x;
    const int tid = threadIdx.x;
    const int lane = tid & 63;
    const int wid = tid >> 6;

    __shared__ float tx0s[N_], ty0s[N_], tx1s[N_], ty1s[N_], tas[N_];
    __shared__ int ms[N_];
    __shared__ double red[256];

    if (tid < N_) {
        const float* t = target_boxes + (size_t)(b * N_ + tid) * 4;
        float x0 = t[0], y0 = t[1], x1 = t[2], y1 = t[3];
        tx0s[tid] = x0; ty0s[tid] = y0; tx1s[tid] = x1; ty1s[tid] = y1;
        tas[tid] = (x1 - x0) * (y1 - y0);
    }
    __syncthreads();

    const float4* pbv = (const float4*)(pred_boxes + (size_t)b * Q_ * 4);

    if (wid == 0) {
        // lane n holds candidate indices for targets n and n+64
        int i1r0 = 0, i1r1 = 0, i2r0 = 0, i2r1 = 0;
        if (lane < N_) {
            i1r0 = (int)(~(unsigned int)c1g[b * N_ + lane]);
            i2r0 = (int)(~(unsigned int)c2g[b * N_ + lane]);
        }
        if (lane + 64 < N_) {
            i1r1 = (int)(~(unsigned int)c1g[b * N_ + lane + 64]);
            i2r1 = (int)(~(unsigned int)c2g[b * N_ + lane + 64]);
        }
        // this lane's pred boxes (for rare masked recompute)
        float px0[KP], py0[KP], px1[KP], py1[KP], pa[KP];
        #pragma unroll
        for (int k = 0; k < KP; ++k) {
            int q = lane + (k << 6);
            px0[k] = py0[k] = px1[k] = py1[k] = pa[k] = 0.0f;
            if (q < Q_) {
                float4 c = pbv[q];
                px0[k] = c.x - 0.5f * c.z; py0[k] = c.y - 0.5f * c.w;
                px1[k] = c.x + 0.5f * c.z; py1[k] = c.y + 0.5f * c.w;
                pa[k] = (px1[k] - px0[k]) * (py1[k] - py0[k]);
            }
        }
        unsigned int myword = 0u;  // used bits for preds [16*lane, 16*lane+16)
        unsigned int um = 0u;      // used bits for this lane's KP preds

        for (int n = 0; n < N_; ++n) {
            int i1v = (n < 64) ? i1r0 : i1r1;
            int i1 = __builtin_amdgcn_readlane(i1v, n & 63);
            bool u1 = __ballot((lane == (i1 >> 4)) && ((myword >> (i1 & 15)) & 1u)) != 0ull;
            int win;
            if (!u1) {
                win = i1;
            } else {
                int i2v = (n < 64) ? i2r0 : i2r1;
                int i2 = __builtin_amdgcn_readlane(i2v, n & 63);
                bool u2 = __ballot((lane == (i2 >> 4)) && ((myword >> (i2 & 15)) & 1u)) != 0ull;
                if (!u2) {
                    win = i2;
                } else {
                    // rare: full masked argmax over unused preds
                    float tx0 = tx0s[n], ty0 = ty0s[n], tx1 = tx1s[n], ty1 = ty1s[n], ta = tas[n];
                    unsigned long long bk = 0ull;
                    #pragma unroll
                    for (int k = 0; k < KP; ++k) {
                        int q = lane + (k << 6);
                        if (q < Q_ && !((um >> k) & 1u)) {
                            float g = giou_f(px0[k], py0[k], px1[k], py1[k], pa[k],
                                             tx0, ty0, tx1, ty1, ta);
                            unsigned long long kk = mkkey(g, q);
                            if (kk > bk) bk = kk;
                        }
                    }
                    #pragma unroll
                    for (int off = 32; off >= 1; off >>= 1) {
                        unsigned long long o = __shfl_xor(bk, off);
                        if (o > bk) bk = o;
                    }
                    win = (int)(~(unsigned int)bk);
                }
            }
            if (lane == (win >> 4)) myword |= 1u << (win & 15);
            if (lane == (win & 63)) um |= 1u << (win >> 6);
            if (lane == 0) ms[n] = win;
        }
    }
    __syncthreads();

    double acc = 0.0;

    // box losses: one target per thread (tid < 100)
    if (tid < N_) {
        int n = tid;
        int q = ms[n];
        float4 c = pbv[q];
        float tx0 = tx0s[n], ty0 = ty0s[n], tx1 = tx1s[n], ty1 = ty1s[n];
        float tcx = (tx0 + tx1) * 0.5f, tcy = (ty0 + ty1) * 0.5f;
        float tw = tx1 - tx0, th = ty1 - ty0;
        float l1 = fabsf(c.x - tcx) + fabsf(c.y - tcy) + fabsf(c.z - tw) + fabsf(c.w - th);
        float x0 = c.x - 0.5f * c.z, y0 = c.y - 0.5f * c.w;
        float x1 = c.x + 0.5f * c.z, y1 = c.y + 0.5f * c.w;
        float pa = (x1 - x0) * (y1 - y0);
        float g = giou_f(x0, y0, x1, y1, pa, tx0, ty0, tx1, ty1, tas[n]);
        acc += (double)(BOX_W * l1) + (double)(GIOU_W * (1.0f - g));
    }

    // BCE: thread tid owns class tid for all 100 rows (coalesced 256B/wave)
    {
        double a0 = 0.0, a1 = 0.0;
        #pragma unroll 4
        for (int n = 0; n < N_; ++n) {
            int q = ms[n];
            int lab = target_labels[b * N_ + n];
            float x = pred_logits[((size_t)(b * Q_ + q)) * C_ + tid];
            float t = (tid == lab) ? 1.0f : 0.0f;
            float term = fmaxf(x, 0.0f) - x * t + log1pf(expf(-fabsf(x)));
            if (n & 1) a1 += (double)term; else a0 += (double)term;
        }
        acc += (double)CLS_W * (a0 + a1);
    }

    red[tid] = acc;
    __syncthreads();
    #pragma unroll
    for (int s = 128; s >= 1; s >>= 1) {
        if (tid < s) red[tid] += red[tid + s];
        __syncthreads();
    }
    if (tid == 0) partial[b] = red[0];
}

// ---------------- kernel 3: final reduce ----------------
__global__ __launch_bounds__(64) void finalize_kernel(
    const double* __restrict__ partial, float* __restrict__ out)
{
    const int lane = threadIdx.x;
    double acc = partial[lane];
    #pragma unroll
    for (int off = 32; off >= 1; off >>= 1) acc += __shfl_xor(acc, off);
    if (lane == 0) out[0] = (float)(acc / (double)(B_ * N_));
}

extern "C" void kernel_launch(void* const* d_in, const int* in_sizes, int n_in,
                              void* d_out, int out_size, void* d_ws, size_t ws_size,
                              hipStream_t stream) {
    const float* pred_boxes    = (const float*)d_in[0];
    const float* pred_logits   = (const float*)d_in[1];
    const float* target_boxes  = (const float*)d_in[2];
    const int*   target_labels = (const int*)d_in[3];
    float* out = (float*)d_out;

    char* ws = (char*)d_ws;
    unsigned long long* c1 = (unsigned long long*)(ws);          // 6400*8
    unsigned long long* c2 = (unsigned long long*)(ws + 51200);  // 6400*8
    double* partial = (double*)(ws + 102400);                    // 64*8

    hipLaunchKernelGGL(cand_kernel, dim3(B_ * N_), dim3(64), 0, stream,
                       pred_boxes, target_boxes, c1, c2);
    hipLaunchKernelGGL(resolve_loss_kernel, dim3(B_), dim3(256), 0, stream,
                       pred_boxes, pred_logits, target_boxes, target_labels, c1, c2, partial);
    hipLaunchKernelGGL(finalize_kernel, dim3(1), dim3(64), 0, stream, partial, out);
}

// Round 4
// 59.629 us; speedup vs baseline: 1.2419x; 1.2419x over previous
//
#include <hip/hip_runtime.h>
#include <math.h>

constexpr int B_ = 64, Q_ = 900, N_ = 100, C_ = 256;
constexpr float EPSF = 1e-6f;
constexpr float BOX_W = 5.0f, GIOU_W = 2.0f, CLS_W = 1.0f;
constexpr int KP = 15;  // preds per lane: 64 lanes * 15 >= 900
typedef unsigned long long u64;

__device__ __forceinline__ float giou_f(float px0, float py0, float px1, float py1, float pa,
                                        float tx0, float ty0, float tx1, float ty1, float ta) {
    float ltx = fmaxf(px0, tx0), lty = fmaxf(py0, ty0);
    float rbx = fminf(px1, tx1), rby = fminf(py1, ty1);
    float w = fmaxf(rbx - ltx, 0.0f), h = fmaxf(rby - lty, 0.0f);
    float inter = w * h;
    float uni = pa + ta - inter;
    float iou = inter / (uni + EPSF);
    float ex0 = fminf(px0, tx0), ey0 = fminf(py0, ty0);
    float ex1 = fmaxf(px1, tx1), ey1 = fmaxf(py1, ty1);
    float ew = fmaxf(ex1 - ex0, 0.0f), eh = fmaxf(ey1 - ey0, 0.0f);
    float earea = ew * eh;
    return iou - (earea - uni) / (earea + EPSF);
}

// order-preserving float->uint; key = (ord << 32) | ~q  => u64 max == (max value, min index)
__device__ __forceinline__ unsigned int f2ord(float f) {
    unsigned int u = __float_as_uint(f);
    return (u & 0x80000000u) ? ~u : (u | 0x80000000u);
}
__device__ __forceinline__ u64 mkkey(float g, int q) {
    return ((u64)f2ord(g) << 32) | (unsigned int)(~(unsigned int)q);
}
__device__ __forceinline__ int keyidx(u64 k) { return (int)(~(unsigned int)k); }

// compare-exchange, descending (x keeps max)
__device__ __forceinline__ void ce_desc(u64& x, u64& y) {
    u64 mx = (x > y) ? x : y;
    u64 mn = (x > y) ? y : x;
    x = mx; y = mn;
}

// ---------------- kernel 1: per-column exact top-4 ----------------
// grid: 1600 blocks x 256 threads; block handles 4 targets (one per wave)
__global__ __launch_bounds__(256) void cand_kernel(
    const float* __restrict__ pred_boxes,   // [B,Q,4] cxcywh
    const float* __restrict__ target_boxes, // [B,N,4] xyxy
    u64* __restrict__ cands)                // [B*N*4]
{
    const int blk = blockIdx.x;
    const int b = blk / 25;
    const int wave = threadIdx.x >> 6;
    const int lane = threadIdx.x & 63;
    const int n = (blk % 25) * 4 + wave;
    const int bn = b * N_ + n;

    const float* t = target_boxes + (size_t)bn * 4;
    float tx0 = t[0], ty0 = t[1], tx1 = t[2], ty1 = t[3];
    float ta = (tx1 - tx0) * (ty1 - ty0);

    const float4* pbv = (const float4*)(pred_boxes + (size_t)b * Q_ * 4);
    u64 a0 = 0, a1 = 0, a2 = 0, a3 = 0;   // sorted descending
    #pragma unroll
    for (int k = 0; k < KP; ++k) {
        int q = lane + (k << 6);
        if (q < Q_) {
            float4 c = pbv[q];
            float x0 = c.x - 0.5f * c.z, y0 = c.y - 0.5f * c.w;
            float x1 = c.x + 0.5f * c.z, y1 = c.y + 0.5f * c.w;
            float pa = (x1 - x0) * (y1 - y0);
            float g = giou_f(x0, y0, x1, y1, pa, tx0, ty0, tx1, ty1, ta);
            u64 kk = mkkey(g, q);
            if (kk > a0)      { a3 = a2; a2 = a1; a1 = a0; a0 = kk; }
            else if (kk > a1) { a3 = a2; a2 = a1; a1 = kk; }
            else if (kk > a2) { a3 = a2; a2 = kk; }
            else if (kk > a3) { a3 = kk; }
        }
    }
    // butterfly reduce keeping exact top-4 (bitonic half-cleaner + 4-sort)
    #pragma unroll
    for (int off = 32; off >= 1; off >>= 1) {
        u64 b0 = __shfl_xor(a0, off);
        u64 b1 = __shfl_xor(a1, off);
        u64 b2 = __shfl_xor(a2, off);
        u64 b3 = __shfl_xor(a3, off);
        u64 m0 = (a0 > b3) ? a0 : b3;
        u64 m1 = (a1 > b2) ? a1 : b2;
        u64 m2 = (a2 > b1) ? a2 : b1;
        u64 m3 = (a3 > b0) ? a3 : b0;
        ce_desc(m0, m2); ce_desc(m1, m3);
        ce_desc(m0, m1); ce_desc(m2, m3);
        a0 = m0; a1 = m1; a2 = m2; a3 = m3;
    }
    u64 v = (lane == 0) ? a0 : (lane == 1) ? a1 : (lane == 2) ? a2 : a3;
    if (lane < 4) cands[(size_t)bn * 4 + lane] = v;
}

// -------- kernel 2: register/ballot greedy resolve + box loss --------
__global__ __launch_bounds__(64, 1) void match_kernel(
    const float* __restrict__ pred_boxes,
    const float* __restrict__ target_boxes,
    const u64* __restrict__ cands,
    int* __restrict__ matches,      // [B*N]
    double* __restrict__ box_part)  // [B]
{
    const int b = blockIdx.x;
    const int lane = threadIdx.x;

    __shared__ float tx0s[N_], ty0s[N_], tx1s[N_], ty1s[N_], tas[N_];
    __shared__ int ms[N_];

    for (int n = lane; n < N_; n += 64) {
        const float* t = target_boxes + (size_t)(b * N_ + n) * 4;
        float x0 = t[0], y0 = t[1], x1 = t[2], y1 = t[3];
        tx0s[n] = x0; ty0s[n] = y0; tx1s[n] = x1; ty1s[n] = y1;
        tas[n] = (x1 - x0) * (y1 - y0);
    }

    // lane L holds candidate indices for target L (A) and L+64 (B)
    int rA0 = 0, rA1 = 0, rA2 = 0, rA3 = 0;
    int rB0 = 0, rB1 = 0, rB2 = 0, rB3 = 0;
    if (lane < N_) {
        const u64* p = cands + (size_t)(b * N_ + lane) * 4;
        rA0 = keyidx(p[0]); rA1 = keyidx(p[1]); rA2 = keyidx(p[2]); rA3 = keyidx(p[3]);
    }
    if (lane + 64 < N_) {
        const u64* p = cands + (size_t)(b * N_ + lane + 64) * 4;
        rB0 = keyidx(p[0]); rB1 = keyidx(p[1]); rB2 = keyidx(p[2]); rB3 = keyidx(p[3]);
    }

    // this lane's pred boxes in registers (for rare masked recompute)
    float px0[KP], py0[KP], px1[KP], py1[KP], pa[KP];
    const float4* pbv = (const float4*)(pred_boxes + (size_t)b * Q_ * 4);
    #pragma unroll
    for (int k = 0; k < KP; ++k) {
        int q = lane + (k << 6);
        px0[k] = py0[k] = px1[k] = py1[k] = pa[k] = 0.0f;
        if (q < Q_) {
            float4 c = pbv[q];
            px0[k] = c.x - 0.5f * c.z; py0[k] = c.y - 0.5f * c.w;
            px1[k] = c.x + 0.5f * c.z; py1[k] = c.y + 0.5f * c.w;
            pa[k] = (px1[k] - px0[k]) * (py1[k] - py0[k]);
        }
    }
    __syncthreads();

    unsigned int myword = 0u;  // used bits for preds [16*lane, 16*lane+16)
    unsigned int um = 0u;      // used bits among this lane's KP preds

    for (int n = 0; n < N_; ++n) {
        const int s = n & 63;
        const bool hi = (n >= 64);
        int i0 = __builtin_amdgcn_readlane(hi ? rB0 : rA0, s);
        int win = i0;
        bool u0 = __ballot((lane == (i0 >> 4)) && ((myword >> (i0 & 15)) & 1u)) != 0ull;
        if (u0) {
            int i1 = __builtin_amdgcn_readlane(hi ? rB1 : rA1, s);
            int i2 = __builtin_amdgcn_readlane(hi ? rB2 : rA2, s);
            int i3 = __builtin_amdgcn_readlane(hi ? rB3 : rA3, s);
            bool u1 = __ballot((lane == (i1 >> 4)) && ((myword >> (i1 & 15)) & 1u)) != 0ull;
            bool u2 = __ballot((lane == (i2 >> 4)) && ((myword >> (i2 & 15)) & 1u)) != 0ull;
            bool u3 = __ballot((lane == (i3 >> 4)) && ((myword >> (i3 & 15)) & 1u)) != 0ull;
            if (!u1) win = i1;
            else if (!u2) win = i2;
            else if (!u3) win = i3;
            else {
                // rare: full masked argmax over unused preds
                float tx0 = tx0s[n], ty0 = ty0s[n], tx1 = tx1s[n], ty1 = ty1s[n], ta = tas[n];
                u64 bk = 0ull;
                #pragma unroll
                for (int k = 0; k < KP; ++k) {
                    int q = lane + (k << 6);
                    if (q < Q_ && !((um >> k) & 1u)) {
                        float g = giou_f(px0[k], py0[k], px1[k], py1[k], pa[k],
                                         tx0, ty0, tx1, ty1, ta);
                        u64 kk = mkkey(g, q);
                        if (kk > bk) bk = kk;
                    }
                }
                #pragma unroll
                for (int off = 32; off >= 1; off >>= 1) {
                    u64 o = __shfl_xor(bk, off);
                    if (o > bk) bk = o;
                }
                win = keyidx(bk);
            }
        }
        if (lane == (win >> 4)) myword |= 1u << (win & 15);
        if (lane == (win & 63)) um |= 1u << (win >> 6);
        if (lane == 0) ms[n] = win;
    }
    __syncthreads();

    // box losses: L1 + GIoU on matched pairs; also publish matches
    double acc = 0.0;
    for (int n = lane; n < N_; n += 64) {
        int q = ms[n];
        matches[b * N_ + n] = q;
        float4 c = pbv[q];
        float tx0 = tx0s[n], ty0 = ty0s[n], tx1 = tx1s[n], ty1 = ty1s[n];
        float tcx = (tx0 + tx1) * 0.5f, tcy = (ty0 + ty1) * 0.5f;
        float tw = tx1 - tx0, th = ty1 - ty0;
        float l1 = fabsf(c.x - tcx) + fabsf(c.y - tcy) + fabsf(c.z - tw) + fabsf(c.w - th);
        float x0 = c.x - 0.5f * c.z, y0 = c.y - 0.5f * c.w;
        float x1 = c.x + 0.5f * c.z, y1 = c.y + 0.5f * c.w;
        float pa2 = (x1 - x0) * (y1 - y0);
        float g = giou_f(x0, y0, x1, y1, pa2, tx0, ty0, tx1, ty1, tas[n]);
        acc += (double)(BOX_W * l1) + (double)(GIOU_W * (1.0f - g));
    }
    #pragma unroll
    for (int off = 32; off >= 1; off >>= 1) acc += __shfl_xor(acc, off);
    if (lane == 0) box_part[b] = acc;
}

// ---------------- kernel 3: BCE over gathered logit rows ----------------
__global__ __launch_bounds__(64) void bce_kernel(
    const float* __restrict__ pred_logits,   // [B,Q,C]
    const int* __restrict__ target_labels,   // [B,N]
    const int* __restrict__ matches,         // [B*N]
    double* __restrict__ part)               // [B*N]
{
    const int bn = blockIdx.x;
    const int b = bn / N_;
    const int lane = threadIdx.x;
    const int q = matches[bn];
    const int lab = target_labels[bn];

    const float4* row = (const float4*)(pred_logits + ((size_t)(b * Q_ + q)) * C_);
    float4 v = row[lane];
    int base = lane * 4;
    float xs[4] = {v.x, v.y, v.z, v.w};
    double acc = 0.0;
    #pragma unroll
    for (int j = 0; j < 4; ++j) {
        float x = xs[j];
        float t = (base + j == lab) ? 1.0f : 0.0f;
        float term = fmaxf(x, 0.0f) - x * t + log1pf(expf(-fabsf(x)));
        acc += (double)term;
    }
    #pragma unroll
    for (int off = 32; off >= 1; off >>= 1) acc += __shfl_xor(acc, off);
    if (lane == 0) part[bn] = acc * (double)CLS_W;
}

// ---------------- kernel 4: final reduce ----------------
__global__ __launch_bounds__(256) void finalize_kernel(
    const double* __restrict__ bce_part,  // [B*N]
    const double* __restrict__ box_part,  // [B]
    float* __restrict__ out)
{
    const int tid = threadIdx.x;
    double acc = 0.0;
    for (int i = tid; i < B_ * N_; i += 256) acc += bce_part[i];
    if (tid < B_) acc += box_part[tid];
    __shared__ double red[256];
    red[tid] = acc;
    __syncthreads();
    #pragma unroll
    for (int s = 128; s >= 1; s >>= 1) {
        if (tid < s) red[tid] += red[tid + s];
        __syncthreads();
    }
    if (tid == 0) out[0] = (float)(red[0] / (double)(B_ * N_));
}

extern "C" void kernel_launch(void* const* d_in, const int* in_sizes, int n_in,
                              void* d_out, int out_size, void* d_ws, size_t ws_size,
                              hipStream_t stream) {
    const float* pred_boxes    = (const float*)d_in[0];
    const float* pred_logits   = (const float*)d_in[1];
    const float* target_boxes  = (const float*)d_in[2];
    const int*   target_labels = (const int*)d_in[3];
    float* out = (float*)d_out;

    char* ws = (char*)d_ws;
    u64*    cands    = (u64*)(ws);                 // 6400*4*8 = 204800
    int*    matches  = (int*)(ws + 204800);        // 6400*4  = 25600
    double* bce_part = (double*)(ws + 230400);     // 6400*8  = 51200
    double* box_part = (double*)(ws + 281600);     // 64*8    = 512

    hipLaunchKernelGGL(cand_kernel, dim3(1600), dim3(256), 0, stream,
                       pred_boxes, target_boxes, cands);
    hipLaunchKernelGGL(match_kernel, dim3(B_), dim3(64), 0, stream,
                       pred_boxes, target_boxes, cands, matches, box_part);
    hipLaunchKernelGGL(bce_kernel, dim3(B_ * N_), dim3(64), 0, stream,
                       pred_logits, target_labels, matches, bce_part);
    hipLaunchKernelGGL(finalize_kernel, dim3(1), dim3(256), 0, stream,
                       bce_part, box_part, out);
}